// Round 9
// baseline (225.060 us; speedup 1.0000x reference)
//
#include <hip/hip_runtime.h>

#define N_NODES 50000
#define N_EDGES 800000
#define C 128
#define NCLS 40
#define KB 98          // buckets of 512 dst nodes
#define BCAP 9216      // bucket capacity (mean 8192, fixed input)
#define NB_BIN 196     // bin blocks (4096 edges each)

typedef short bf16x8 __attribute__((ext_vector_type(8)));
typedef float f32x4 __attribute__((ext_vector_type(4)));
typedef unsigned short ushort_t;

__device__ __forceinline__ unsigned short f32_to_bf16(float f) {
    union { float f; unsigned u; } c; c.f = f;
    unsigned r = (c.u + 0x7FFFu + ((c.u >> 16) & 1u)) >> 16;
    return (unsigned short)r;
}
__device__ __forceinline__ float bf_lo(unsigned u) {
    union { unsigned u; float f; } c; c.u = u << 16; return c.f;
}
__device__ __forceinline__ float bf_hi(unsigned u) {
    union { unsigned u; float f; } c; c.u = u & 0xffff0000u; return c.f;
}
__device__ __forceinline__ unsigned pack_bf16(float lo, float hi) {
    return (unsigned)f32_to_bf16(lo) | ((unsigned)f32_to_bf16(hi) << 16);
}

// ---------------- front: edge binning + all weight/feature conversions ----------------
__global__ __launch_bounds__(256)
void front_kernel(const int* __restrict__ src, const int* __restrict__ dst,
                  int* __restrict__ bucket_cnt, unsigned* __restrict__ bucket_data,
                  const float* __restrict__ Wl1, const float* __restrict__ Wr1,
                  const float* __restrict__ Wl2, const float* __restrict__ Wr2,
                  const float* __restrict__ Wc,  const float* __restrict__ x,
                  ushort_t* __restrict__ Wbf1, ushort_t* __restrict__ Wbf2,
                  ushort_t* __restrict__ Wcb,  ushort_t* __restrict__ xb) {
    __shared__ int lh[KB];
    int b = blockIdx.x;
    int tid = threadIdx.x;
    if (b < NB_BIN) {
        int e0 = b * 4096;
        if (tid < KB) lh[tid] = 0;
        __syncthreads();
#pragma unroll
        for (int j = 0; j < 16; ++j) {
            int e = e0 + j * 256 + tid;
            if (e < N_EDGES) atomicAdd(&lh[dst[e] >> 9], 1);
        }
        __syncthreads();
        if (tid < KB) lh[tid] = atomicAdd(&bucket_cnt[tid], lh[tid]);  // base -> cursor
        __syncthreads();
#pragma unroll
        for (int j = 0; j < 16; ++j) {
            int e = e0 + j * 256 + tid;
            if (e < N_EDGES) {
                int d = dst[e];
                int bk = d >> 9;
                int pos = atomicAdd(&lh[bk], 1);
                if (pos < BCAP)
                    bucket_data[bk * BCAP + pos] = (unsigned)src[e] | ((unsigned)(d & 511) << 16);
            }
        }
    } else if (b < NB_BIN + 256) {
        int bb = b - NB_BIN;
        const float* Wl = (bb < 128) ? Wl1 : Wl2;
        const float* Wr = (bb < 128) ? Wr1 : Wr2;
        ushort_t* Bpre  = (bb < 128) ? Wbf1 : Wbf2;
        int idx = (bb & 127) * 256 + tid;      // 32768
        int n = idx >> 8;
        int k = idx & 255;
        float v = (k < 128) ? Wl[k * 128 + n] : Wr[(k - 128) * 128 + n];
        Bpre[n * 256 + k] = f32_to_bf16(v);
    } else if (b < NB_BIN + 280) {
        int idx = (b - (NB_BIN + 256)) * 256 + tid;   // 6144 = 48*128
        if (idx < 48 * 128) {
            int n = idx >> 7;
            int k = idx & 127;
            float v = (n < NCLS) ? Wc[k * NCLS + n] : 0.f;
            Wcb[idx] = f32_to_bf16(v);
        }
    } else {
        int idx = (b - (NB_BIN + 280)) * 256 + tid;   // 800000 = N*C/8
        const float4 v0 = *(const float4*)&x[idx * 8];
        const float4 v1 = *(const float4*)&x[idx * 8 + 4];
        uint4 o;
        o.x = pack_bf16(v0.x, v0.y);
        o.y = pack_bf16(v0.z, v0.w);
        o.z = pack_bf16(v1.x, v1.y);
        o.w = pack_bf16(v1.z, v1.w);
        ((uint4*)xb)[idx] = o;
    }
}

// ---------------- per-bucket CSR build entirely in LDS (512 threads) ----------------
__global__ __launch_bounds__(512)
void build_kernel(const int* __restrict__ bucket_cnt, const unsigned* __restrict__ bucket_data,
                  int* __restrict__ row_ptr, ushort_t* __restrict__ csr16) {
    __shared__ int wt[4];
    __shared__ int wt2[8];
    __shared__ int sbases[128];
    __shared__ int hist[512];
    __shared__ int loff[512];
    __shared__ ushort_t lcsr[BCAP];
    int tid = threadIdx.x;
    int b = blockIdx.x;
    int n0 = b << 9;
    int nb = min(512, N_NODES - n0);

    int v = 0, xs = 0;
    if (tid < 128) {
        v = (tid < KB) ? bucket_cnt[tid] : 0;
        xs = v;
#pragma unroll
        for (int off = 1; off < 64; off <<= 1) {
            int t = __shfl_up(xs, off, 64);
            if ((tid & 63) >= off) xs += t;
        }
        if ((tid & 63) == 63) wt[tid >> 6] = xs;
    }
    hist[tid] = 0;
    __syncthreads();
    if (tid < 128) sbases[tid] = xs - v + ((tid >= 64) ? wt[0] : 0);
    __syncthreads();
    int base = sbases[b];
    int ecnt = min(bucket_cnt[b], BCAP);

    for (int i = tid; i < ecnt; i += 512)
        atomicAdd(&hist[bucket_data[b * BCAP + i] >> 16], 1);
    __syncthreads();

    int h = hist[tid];
    int y = h;
#pragma unroll
    for (int off = 1; off < 64; off <<= 1) {
        int t = __shfl_up(y, off, 64);
        if ((tid & 63) >= off) y += t;
    }
    if ((tid & 63) == 63) wt2[tid >> 6] = y;
    __syncthreads();
    int add = 0;
    for (int j = 0; j < (tid >> 6); ++j) add += wt2[j];
    int ex = y + add - h;
    loff[tid] = ex;
    __syncthreads();

    if (tid < nb) row_ptr[n0 + tid] = base + ex;
    if (b == KB - 1 && tid == 0) row_ptr[N_NODES] = N_EDGES;

    for (int i = tid; i < ecnt; i += 512) {
        unsigned e = bucket_data[b * BCAP + i];
        int pos = atomicAdd(&loff[e >> 16], 1);
        lcsr[pos] = (ushort_t)(e & 0xFFFFu);
    }
    __syncthreads();
    for (int i = tid; i < ecnt; i += 512) csr16[base + i] = lcsr[i];
}

// ---------------- quarter-column gather-reduce (XCD-locality swizzle) ----------------
// Block handles 64 nodes x one 64B column-quarter. quarter = (blockIdx&7)>>1 so,
// under round-robin blockIdx->XCD dispatch, each XCD gathers only a 3.2 MB
// column slice (fully L2-resident). Correct regardless of actual mapping.
// 4 lanes per node (uint4 each = 64 B line per edge), f32 accumulate.
__global__ __launch_bounds__(256)
void aggregate_quarter(const ushort_t* __restrict__ feat,
                       const int* __restrict__ row_ptr,
                       const ushort_t* __restrict__ csr16,
                       ushort_t* __restrict__ agg) {
    int b = blockIdx.x;                  // 3128 = 8 * 391
    int q4 = (b & 7) >> 1;               // quarter 0..3
    int g  = (b >> 3) * 2 + (b & 1);     // node group 0..781
    int tid = threadIdx.x;
    int node = g * 64 + (tid >> 2);
    if (node >= N_NODES) return;
    int off = q4 * 4 + (tid & 3);        // uint4 index within 16-uint4 row
    const uint4* fb = (const uint4*)feat;
    int beg = row_ptr[node];
    int end = row_ptr[node + 1];
    float a0[8], a1[8], a2[8], a3[8];
#pragma unroll
    for (int j = 0; j < 8; ++j) { a0[j] = 0.f; a1[j] = 0.f; a2[j] = 0.f; a3[j] = 0.f; }
    int i = beg;
    for (; i + 4 <= end; i += 4) {
        int s0 = csr16[i + 0];
        int s1 = csr16[i + 1];
        int s2 = csr16[i + 2];
        int s3 = csr16[i + 3];
        uint4 v0 = fb[s0 * 16 + off];
        uint4 v1 = fb[s1 * 16 + off];
        uint4 v2 = fb[s2 * 16 + off];
        uint4 v3 = fb[s3 * 16 + off];
        a0[0] += bf_lo(v0.x); a0[1] += bf_hi(v0.x); a0[2] += bf_lo(v0.y); a0[3] += bf_hi(v0.y);
        a0[4] += bf_lo(v0.z); a0[5] += bf_hi(v0.z); a0[6] += bf_lo(v0.w); a0[7] += bf_hi(v0.w);
        a1[0] += bf_lo(v1.x); a1[1] += bf_hi(v1.x); a1[2] += bf_lo(v1.y); a1[3] += bf_hi(v1.y);
        a1[4] += bf_lo(v1.z); a1[5] += bf_hi(v1.z); a1[6] += bf_lo(v1.w); a1[7] += bf_hi(v1.w);
        a2[0] += bf_lo(v2.x); a2[1] += bf_hi(v2.x); a2[2] += bf_lo(v2.y); a2[3] += bf_hi(v2.y);
        a2[4] += bf_lo(v2.z); a2[5] += bf_hi(v2.z); a2[6] += bf_lo(v2.w); a2[7] += bf_hi(v2.w);
        a3[0] += bf_lo(v3.x); a3[1] += bf_hi(v3.x); a3[2] += bf_lo(v3.y); a3[3] += bf_hi(v3.y);
        a3[4] += bf_lo(v3.z); a3[5] += bf_hi(v3.z); a3[6] += bf_lo(v3.w); a3[7] += bf_hi(v3.w);
    }
    int rem = end - i;   // 0..3, masked parallel tail
    if (rem > 0) {
        int s0 = csr16[i];
        int s1 = csr16[i + (rem > 1 ? 1 : 0)];
        int s2 = csr16[i + (rem > 2 ? 2 : 0)];
        uint4 v0 = fb[s0 * 16 + off];
        uint4 v1 = fb[s1 * 16 + off];
        uint4 v2 = fb[s2 * 16 + off];
        float m1 = rem > 1 ? 1.f : 0.f;
        float m2 = rem > 2 ? 1.f : 0.f;
        a0[0] += bf_lo(v0.x); a0[1] += bf_hi(v0.x); a0[2] += bf_lo(v0.y); a0[3] += bf_hi(v0.y);
        a0[4] += bf_lo(v0.z); a0[5] += bf_hi(v0.z); a0[6] += bf_lo(v0.w); a0[7] += bf_hi(v0.w);
        a1[0] += m1 * bf_lo(v1.x); a1[1] += m1 * bf_hi(v1.x); a1[2] += m1 * bf_lo(v1.y); a1[3] += m1 * bf_hi(v1.y);
        a1[4] += m1 * bf_lo(v1.z); a1[5] += m1 * bf_hi(v1.z); a1[6] += m1 * bf_lo(v1.w); a1[7] += m1 * bf_hi(v1.w);
        a2[0] += m2 * bf_lo(v2.x); a2[1] += m2 * bf_hi(v2.x); a2[2] += m2 * bf_lo(v2.y); a2[3] += m2 * bf_hi(v2.y);
        a2[4] += m2 * bf_lo(v2.z); a2[5] += m2 * bf_hi(v2.z); a2[6] += m2 * bf_lo(v2.w); a2[7] += m2 * bf_hi(v2.w);
    }
    int d = end - beg;
    float di = d > 0 ? 1.f / (float)d : 0.f;
    float r[8];
#pragma unroll
    for (int j = 0; j < 8; ++j) r[j] = (a0[j] + a1[j] + a2[j] + a3[j]) * di;
    uint4 o;
    o.x = pack_bf16(r[0], r[1]);
    o.y = pack_bf16(r[2], r[3]);
    o.z = pack_bf16(r[4], r[5]);
    o.w = pack_bf16(r[6], r[7]);
    ((uint4*)agg)[node * 16 + off] = o;
}

// ---------------- layer GEMM: out = relu([agg | feat] @ [Wl;Wr] + b)  (+classifier) ----------------
#define ATS 264   // A tile row stride in shorts (528 B, 16B-aligned)
template<int CLS>
__global__ __launch_bounds__(256)
void gemm_layer(const ushort_t* __restrict__ aggb, const ushort_t* __restrict__ feat,
                const ushort_t* __restrict__ Bpre, const float* __restrict__ bias,
                ushort_t* __restrict__ hout,
                const ushort_t* __restrict__ Wcb, const float* __restrict__ bc,
                float* __restrict__ out) {
    __shared__ ushort_t At[64 * ATS];      // 33 KB; holds [agg | x], later h2 tile (CLS)
    __shared__ ushort_t Bs[2][128 * 40];   // 20 KB, double-buffered W chunks / Wc planes
    const int tid = threadIdx.x;
    const int r0 = blockIdx.x * 64;
    const int w = tid >> 6, lane = tid & 63, m = lane & 15, quad = lane >> 4;

    const uint4* au = (const uint4*)aggb;
    const uint4* fu = (const uint4*)feat;
#pragma unroll
    for (int i = 0; i < 8; ++i) {
        int slot = tid + i * 256;
        int row = slot >> 5, u = slot & 31;
        int rg = r0 + row; if (rg >= N_NODES) rg = N_NODES - 1;
        uint4 vv = (u < 16) ? au[rg * 16 + u] : fu[rg * 16 + (u - 16)];
        *(uint4*)&At[row * ATS + u * 8] = vv;
    }
#pragma unroll
    for (int i = 0; i < 2; ++i) {
        int slot = tid + i * 256;
        int n = slot >> 2, qq = slot & 3;
        *(uint4*)&Bs[0][n * 40 + qq * 8] = *(const uint4*)&Bpre[n * 256 + qq * 8];
    }
    __syncthreads();

    f32x4 acc[8];
#pragma unroll
    for (int t = 0; t < 8; ++t) acc[t] = (f32x4){0.f, 0.f, 0.f, 0.f};

    for (int kc = 0; kc < 8; ++kc) {
        if (kc < 7) {
#pragma unroll
            for (int i = 0; i < 2; ++i) {   // prefetch next B chunk into other buffer
                int slot = tid + i * 256;
                int n = slot >> 2, qq = slot & 3;
                *(uint4*)&Bs[(kc + 1) & 1][n * 40 + qq * 8] =
                    *(const uint4*)&Bpre[n * 256 + (kc + 1) * 32 + qq * 8];
            }
        }
        bf16x8 af = *(const bf16x8*)&At[(w * 16 + m) * ATS + kc * 32 + quad * 8];
#pragma unroll
        for (int t = 0; t < 8; ++t) {
            bf16x8 bf = *(const bf16x8*)&Bs[kc & 1][(t * 16 + m) * 40 + quad * 8];
            acc[t] = __builtin_amdgcn_mfma_f32_16x16x32_bf16(af, bf, acc[t], 0, 0, 0);
        }
        __syncthreads();
    }

    if (CLS == 0) {
#pragma unroll
        for (int t = 0; t < 8; ++t) {
            int colv = t * 16 + m;
            float bv = bias[colv];
#pragma unroll
            for (int reg = 0; reg < 4; ++reg) {
                int rg = r0 + w * 16 + quad * 4 + reg;
                if (rg < N_NODES) {
                    float vv = fmaxf(acc[t][reg] + bv, 0.f);
                    hout[rg * C + colv] = f32_to_bf16(vv);
                }
            }
        }
    } else {
#pragma unroll
        for (int t = 0; t < 8; ++t) {
            int colv = t * 16 + m;
            float bv = bias[colv];
#pragma unroll
            for (int reg = 0; reg < 4; ++reg) {
                int rl = w * 16 + quad * 4 + reg;
                float vv = fmaxf(acc[t][reg] + bv, 0.f);
                At[rl * ATS + colv] = f32_to_bf16(vv);
            }
        }
        ushort_t* wcs = &Bs[0][0];   // 4 planes x 48x40 = 15360 shorts
#pragma unroll
        for (int i = 0; i < 3; ++i) {
            int slot = tid + i * 256;           // 768 = 48 rows x 16 uint4
            int n = slot >> 4, kq = slot & 15;
            uint4 vv = *(const uint4*)&Wcb[n * C + kq * 8];
            *(uint4*)&wcs[(kq >> 2) * (48 * 40) + n * 40 + (kq & 3) * 8] = vv;
        }
        __syncthreads();
        f32x4 acc2[3];
#pragma unroll
        for (int t = 0; t < 3; ++t) acc2[t] = (f32x4){0.f, 0.f, 0.f, 0.f};
#pragma unroll
        for (int kc = 0; kc < 4; ++kc) {
            bf16x8 af = *(const bf16x8*)&At[(w * 16 + m) * ATS + kc * 32 + quad * 8];
#pragma unroll
            for (int t = 0; t < 3; ++t) {
                bf16x8 bf = *(const bf16x8*)&wcs[kc * (48 * 40) + (t * 16 + m) * 40 + quad * 8];
                acc2[t] = __builtin_amdgcn_mfma_f32_16x16x32_bf16(af, bf, acc2[t], 0, 0, 0);
            }
        }
#pragma unroll
        for (int t = 0; t < 3; ++t) {
            int col = t * 16 + m;
            if (col < NCLS) {
                float bvv = bc[col];
#pragma unroll
                for (int reg = 0; reg < 4; ++reg) {
                    int rg = r0 + w * 16 + quad * 4 + reg;
                    if (rg < N_NODES) out[rg * NCLS + col] = acc2[t][reg] + bvv;
                }
            }
        }
    }
}

extern "C" void kernel_launch(void* const* d_in, const int* in_sizes, int n_in,
                              void* d_out, int out_size, void* d_ws, size_t ws_size,
                              hipStream_t stream) {
    const float* x   = (const float*)d_in[0];
    const int*   ei  = (const int*)d_in[1];
    const float* Wl1 = (const float*)d_in[2];
    const float* Wr1 = (const float*)d_in[3];
    const float* b1  = (const float*)d_in[4];
    const float* Wl2 = (const float*)d_in[5];
    const float* Wr2 = (const float*)d_in[6];
    const float* b2  = (const float*)d_in[7];
    const float* Wc  = (const float*)d_in[8];
    const float* bc  = (const float*)d_in[9];
    const int* srcI = ei;              // edge_index[0]
    const int* dstI = ei + N_EDGES;    // edge_index[1]
    float* out = (float*)d_out;

    // workspace layout
    ushort_t* xb   = (ushort_t*)d_ws;                 // N*C bf16
    ushort_t* h1b  = xb + (size_t)N_NODES * C;        // N*C bf16
    ushort_t* aggb = h1b + (size_t)N_NODES * C;       // N*C bf16
    ushort_t* Wbf1 = aggb + (size_t)N_NODES * C;      // 32768
    ushort_t* Wbf2 = Wbf1 + 32768;                    // 32768
    ushort_t* Wcb  = Wbf2 + 32768;                    // 6144
    ushort_t* csr16 = Wcb + 6144;                     // E (uint16)
    int* bucket_cnt = (int*)(csr16 + N_EDGES);        // 128
    int* row_ptr    = bucket_cnt + 128;               // N+1
    unsigned* bucket_data = (unsigned*)(row_ptr + N_NODES + 1);  // KB*BCAP

    // ---- front: bin (critical path) + all conversions, one launch ----
    hipMemsetAsync(bucket_cnt, 0, 128 * sizeof(int), stream);
    front_kernel<<<NB_BIN + 280 + (N_NODES * C / 8) / 256, 256, 0, stream>>>(
        srcI, dstI, bucket_cnt, bucket_data,
        Wl1, Wr1, Wl2, Wr2, Wc, x, Wbf1, Wbf2, Wcb, xb);

    // ---- CSR build ----
    build_kernel<<<KB, 512, 0, stream>>>(bucket_cnt, bucket_data, row_ptr, csr16);

    // ---- layer 1 ----  (3128 blocks = 8 * 391; node-group = (b>>3)*2 + (b&1))
    aggregate_quarter<<<3128, 256, 0, stream>>>(xb, row_ptr, csr16, aggb);
    gemm_layer<0><<<(N_NODES + 63) / 64, 256, 0, stream>>>(
        aggb, xb, Wbf1, b1, h1b, nullptr, nullptr, nullptr);

    // ---- layer 2 + classifier ----
    aggregate_quarter<<<3128, 256, 0, stream>>>(h1b, row_ptr, csr16, aggb);
    gemm_layer<1><<<(N_NODES + 63) / 64, 256, 0, stream>>>(
        aggb, h1b, Wbf2, b2, nullptr, Wcb, bc, out);
}

// Round 10
// 204.473 us; speedup vs baseline: 1.1007x; 1.1007x over previous
//
#include <hip/hip_runtime.h>

#define N_NODES 50000
#define N_EDGES 800000
#define C 128
#define NCLS 40
#define KB 98          // buckets of 512 dst nodes
#define BCAP 9216      // bucket capacity (mean 8192, fixed input)

typedef short bf16x8 __attribute__((ext_vector_type(8)));
typedef float f32x4 __attribute__((ext_vector_type(4)));
typedef unsigned short ushort_t;

__device__ __forceinline__ unsigned short f32_to_bf16(float f) {
    union { float f; unsigned u; } c; c.f = f;
    unsigned r = (c.u + 0x7FFFu + ((c.u >> 16) & 1u)) >> 16;
    return (unsigned short)r;
}
__device__ __forceinline__ float bf_lo(unsigned u) {
    union { unsigned u; float f; } c; c.u = u << 16; return c.f;
}
__device__ __forceinline__ float bf_hi(unsigned u) {
    union { unsigned u; float f; } c; c.u = u & 0xffff0000u; return c.f;
}
__device__ __forceinline__ unsigned pack_bf16(float lo, float hi) {
    return (unsigned)f32_to_bf16(lo) | ((unsigned)f32_to_bf16(hi) << 16);
}

// ---------------- all weight/feature conversions in one launch ----------------
// blocks 0..127: W1 -> Wbf1 [n][256] ; 128..255: W2 ; 256..279: Wc -> [48][128];
// 280..3404: x f32 -> bf16
__global__ __launch_bounds__(256)
void convert_all(const float* __restrict__ Wl1, const float* __restrict__ Wr1,
                 const float* __restrict__ Wl2, const float* __restrict__ Wr2,
                 const float* __restrict__ Wc,  const float* __restrict__ x,
                 ushort_t* __restrict__ Wbf1, ushort_t* __restrict__ Wbf2,
                 ushort_t* __restrict__ Wcb,  ushort_t* __restrict__ xb) {
    int b = blockIdx.x;
    int tid = threadIdx.x;
    if (b < 256) {
        const float* Wl = (b < 128) ? Wl1 : Wl2;
        const float* Wr = (b < 128) ? Wr1 : Wr2;
        ushort_t* Bpre  = (b < 128) ? Wbf1 : Wbf2;
        int idx = (b & 127) * 256 + tid;       // 32768
        int n = idx >> 8;
        int k = idx & 255;
        float v = (k < 128) ? Wl[k * 128 + n] : Wr[(k - 128) * 128 + n];
        Bpre[n * 256 + k] = f32_to_bf16(v);
    } else if (b < 280) {
        int idx = (b - 256) * 256 + tid;       // 6144 = 48*128
        if (idx < 48 * 128) {
            int n = idx >> 7;
            int k = idx & 127;
            float v = (n < NCLS) ? Wc[k * NCLS + n] : 0.f;
            Wcb[idx] = f32_to_bf16(v);
        }
    } else {
        int idx = (b - 280) * 256 + tid;       // N*C/8 = 800000
        const float4 v0 = *(const float4*)&x[idx * 8];
        const float4 v1 = *(const float4*)&x[idx * 8 + 4];
        uint4 o;
        o.x = pack_bf16(v0.x, v0.y);
        o.y = pack_bf16(v0.z, v0.w);
        o.z = pack_bf16(v1.x, v1.y);
        o.w = pack_bf16(v1.z, v1.w);
        ((uint4*)xb)[idx] = o;
    }
}

// ---------------- pass 1: bin edges by dst>>9, LDS write-combined ----------------
__global__ __launch_bounds__(256)
void bin_kernel(const int* __restrict__ src, const int* __restrict__ dst,
                int* __restrict__ bucket_cnt, unsigned* __restrict__ bucket_data) {
    __shared__ int lh[KB];
    int tid = threadIdx.x;
    int e0 = blockIdx.x * 4096;
    if (tid < KB) lh[tid] = 0;
    __syncthreads();
#pragma unroll
    for (int j = 0; j < 16; ++j) {
        int e = e0 + j * 256 + tid;
        if (e < N_EDGES) atomicAdd(&lh[dst[e] >> 9], 1);
    }
    __syncthreads();
    if (tid < KB) lh[tid] = atomicAdd(&bucket_cnt[tid], lh[tid]);  // block base -> cursor
    __syncthreads();
#pragma unroll
    for (int j = 0; j < 16; ++j) {
        int e = e0 + j * 256 + tid;
        if (e < N_EDGES) {
            int d = dst[e];
            int b = d >> 9;
            int pos = atomicAdd(&lh[b], 1);
            if (pos < BCAP)
                bucket_data[b * BCAP + pos] = (unsigned)src[e] | ((unsigned)(d & 511) << 16);
        }
    }
}

// ---------------- pass 2: per-bucket CSR build entirely in LDS ----------------
__global__ __launch_bounds__(256)
void build_kernel(const int* __restrict__ bucket_cnt, const unsigned* __restrict__ bucket_data,
                  int* __restrict__ row_ptr, ushort_t* __restrict__ csr16) {
    __shared__ int wt[4];
    __shared__ int wt2[4];
    __shared__ int sbases[128];
    __shared__ int hist[512];
    __shared__ int loff[512];
    __shared__ ushort_t lcsr[BCAP];
    int tid = threadIdx.x;
    int b = blockIdx.x;
    int n0 = b << 9;
    int nb = min(512, N_NODES - n0);

    int v = 0, x = 0;
    if (tid < 128) {
        v = (tid < KB) ? bucket_cnt[tid] : 0;
        x = v;
#pragma unroll
        for (int off = 1; off < 64; off <<= 1) {
            int t = __shfl_up(x, off, 64);
            if ((tid & 63) >= off) x += t;
        }
        if ((tid & 63) == 63) wt[tid >> 6] = x;
    }
    hist[tid] = 0; hist[tid + 256] = 0;
    __syncthreads();
    if (tid < 128) sbases[tid] = x - v + ((tid >= 64) ? wt[0] : 0);
    __syncthreads();
    int base = sbases[b];
    int ecnt = min(bucket_cnt[b], BCAP);

    for (int i = tid; i < ecnt; i += 256)
        atomicAdd(&hist[bucket_data[b * BCAP + i] >> 16], 1);
    __syncthreads();

    int h0 = hist[2 * tid], h1 = hist[2 * tid + 1];
    int s = h0 + h1;
    int y = s;
#pragma unroll
    for (int off = 1; off < 64; off <<= 1) {
        int t = __shfl_up(y, off, 64);
        if ((tid & 63) >= off) y += t;
    }
    if ((tid & 63) == 63) wt2[tid >> 6] = y;
    __syncthreads();
    int add = 0;
    for (int j = 0; j < (tid >> 6); ++j) add += wt2[j];
    int ex = y + add - s;
    loff[2 * tid] = ex;
    loff[2 * tid + 1] = ex + h0;
    __syncthreads();

    for (int n = tid; n < nb; n += 256) row_ptr[n0 + n] = base + loff[n];
    if (b == KB - 1 && tid == 0) row_ptr[N_NODES] = N_EDGES;
    __syncthreads();

    for (int i = tid; i < ecnt; i += 256) {
        unsigned e = bucket_data[b * BCAP + i];
        int pos = atomicAdd(&loff[e >> 16], 1);
        lcsr[pos] = (ushort_t)(e & 0xFFFFu);
    }
    __syncthreads();
    for (int i = tid; i < ecnt; i += 256) csr16[base + i] = lcsr[i];
}

// ---------------- fused layer: aggregate(64 nodes) + SAGE GEMM (+classifier) ----------------
// aggL row stride 136 shorts (272 B: 16B-aligned rows, 2-way-max bank aliasing)
#define ALD 136
template<int CLS>
__global__ __launch_bounds__(256)
void fused_layer(const ushort_t* __restrict__ feat,
                 const int* __restrict__ row_ptr,
                 const ushort_t* __restrict__ csr16,
                 const ushort_t* __restrict__ Bpre,
                 const float* __restrict__ bias,
                 ushort_t* __restrict__ hout,
                 const ushort_t* __restrict__ Wcb,
                 const float* __restrict__ bc,
                 float* __restrict__ out) {
    __shared__ ushort_t aggL[64 * ALD];          // agg tile, later h2 tile (CLS)
    __shared__ ushort_t stg[64 * 40 + 128 * 40]; // AsX | Bs ; later Wc planes (CLS)
    ushort_t* AsX = stg;
    ushort_t* BsP = stg + 64 * 40;
    const int tid = threadIdx.x;
    const int r0 = blockIdx.x * 64;
    const int w = tid >> 6, lane = tid & 63, m = lane & 15, quad = lane >> 4;

    // ---- phase 1: gather-aggregate 64 nodes in 4 passes of 16 ----
    const uint4* fb = (const uint4*)feat;
    const int q = tid & 15;
    for (int p = 0; p < 4; ++p) {
        int nl = p * 16 + (tid >> 4);
        int node = r0 + nl;
        int beg = 0, end = 0;
        if (node < N_NODES) { beg = row_ptr[node]; end = row_ptr[node + 1]; }
        float a0[8], a1[8], a2[8], a3[8];
#pragma unroll
        for (int j = 0; j < 8; ++j) { a0[j] = 0.f; a1[j] = 0.f; a2[j] = 0.f; a3[j] = 0.f; }
        int i = beg;
        for (; i + 4 <= end; i += 4) {
            int s0 = csr16[i + 0];
            int s1 = csr16[i + 1];
            int s2 = csr16[i + 2];
            int s3 = csr16[i + 3];
            uint4 v0 = fb[s0 * 16 + q];
            uint4 v1 = fb[s1 * 16 + q];
            uint4 v2 = fb[s2 * 16 + q];
            uint4 v3 = fb[s3 * 16 + q];
            a0[0] += bf_lo(v0.x); a0[1] += bf_hi(v0.x); a0[2] += bf_lo(v0.y); a0[3] += bf_hi(v0.y);
            a0[4] += bf_lo(v0.z); a0[5] += bf_hi(v0.z); a0[6] += bf_lo(v0.w); a0[7] += bf_hi(v0.w);
            a1[0] += bf_lo(v1.x); a1[1] += bf_hi(v1.x); a1[2] += bf_lo(v1.y); a1[3] += bf_hi(v1.y);
            a1[4] += bf_lo(v1.z); a1[5] += bf_hi(v1.z); a1[6] += bf_lo(v1.w); a1[7] += bf_hi(v1.w);
            a2[0] += bf_lo(v2.x); a2[1] += bf_hi(v2.x); a2[2] += bf_lo(v2.y); a2[3] += bf_hi(v2.y);
            a2[4] += bf_lo(v2.z); a2[5] += bf_hi(v2.z); a2[6] += bf_lo(v2.w); a2[7] += bf_hi(v2.w);
            a3[0] += bf_lo(v3.x); a3[1] += bf_hi(v3.x); a3[2] += bf_lo(v3.y); a3[3] += bf_hi(v3.y);
            a3[4] += bf_lo(v3.z); a3[5] += bf_hi(v3.z); a3[6] += bf_lo(v3.w); a3[7] += bf_hi(v3.w);
        }
        int rem = end - i;
        if (rem > 0) {
            int s0 = csr16[i];
            int s1 = csr16[i + (rem > 1 ? 1 : 0)];
            int s2 = csr16[i + (rem > 2 ? 2 : 0)];
            uint4 v0 = fb[s0 * 16 + q];
            uint4 v1 = fb[s1 * 16 + q];
            uint4 v2 = fb[s2 * 16 + q];
            float m1 = rem > 1 ? 1.f : 0.f;
            float m2 = rem > 2 ? 1.f : 0.f;
            a0[0] += bf_lo(v0.x); a0[1] += bf_hi(v0.x); a0[2] += bf_lo(v0.y); a0[3] += bf_hi(v0.y);
            a0[4] += bf_lo(v0.z); a0[5] += bf_hi(v0.z); a0[6] += bf_lo(v0.w); a0[7] += bf_hi(v0.w);
            a1[0] += m1 * bf_lo(v1.x); a1[1] += m1 * bf_hi(v1.x); a1[2] += m1 * bf_lo(v1.y); a1[3] += m1 * bf_hi(v1.y);
            a1[4] += m1 * bf_lo(v1.z); a1[5] += m1 * bf_hi(v1.z); a1[6] += m1 * bf_lo(v1.w); a1[7] += m1 * bf_hi(v1.w);
            a2[0] += m2 * bf_lo(v2.x); a2[1] += m2 * bf_hi(v2.x); a2[2] += m2 * bf_lo(v2.y); a2[3] += m2 * bf_hi(v2.y);
            a2[4] += m2 * bf_lo(v2.z); a2[5] += m2 * bf_hi(v2.z); a2[6] += m2 * bf_lo(v2.w); a2[7] += m2 * bf_hi(v2.w);
        }
        int d = end - beg;
        float di = d > 0 ? 1.f / (float)d : 0.f;
        float r[8];
#pragma unroll
        for (int j = 0; j < 8; ++j) r[j] = (a0[j] + a1[j] + a2[j] + a3[j]) * di;
        uint4 o;
        o.x = pack_bf16(r[0], r[1]);
        o.y = pack_bf16(r[2], r[3]);
        o.z = pack_bf16(r[4], r[5]);
        o.w = pack_bf16(r[6], r[7]);
        *(uint4*)&aggL[nl * ALD + q * 8] = o;
    }
    __syncthreads();

    // ---- phase 2: GEMM  out = relu([agg | feat] @ [Wl;Wr] + b) ----
    f32x4 acc[8];
#pragma unroll
    for (int t = 0; t < 8; ++t) acc[t] = (f32x4){0.f, 0.f, 0.f, 0.f};

    for (int kc = 0; kc < 8; ++kc) {
        if (kc) __syncthreads();              // previous MFMA done reading stg
        if (kc >= 4) {                        // stage xin rows 64x32
            int row = tid >> 2;
            int kq = tid & 3;
            int rg = r0 + row; if (rg >= N_NODES) rg = N_NODES - 1;
            uint4 v = *(const uint4*)&feat[rg * C + (kc & 3) * 32 + kq * 8];
            *(uint4*)&AsX[row * 40 + kq * 8] = v;
        }
#pragma unroll
        for (int i = 0; i < 2; ++i) {         // stage W 128x32
            int slot = tid + i * 256;
            int n = slot >> 2;
            int qq = slot & 3;
            *(uint4*)&BsP[n * 40 + qq * 8] = *(const uint4*)&Bpre[n * 256 + kc * 32 + qq * 8];
        }
        __syncthreads();
        bf16x8 af = (kc < 4)
            ? *(const bf16x8*)&aggL[(w * 16 + m) * ALD + kc * 32 + quad * 8]
            : *(const bf16x8*)&AsX[(w * 16 + m) * 40 + quad * 8];
#pragma unroll
        for (int t = 0; t < 8; ++t) {
            bf16x8 bf = *(const bf16x8*)&BsP[(t * 16 + m) * 40 + quad * 8];
            acc[t] = __builtin_amdgcn_mfma_f32_16x16x32_bf16(af, bf, acc[t], 0, 0, 0);
        }
    }

    if (CLS == 0) {
        // epilogue: relu+bias, bf16 store. C/D: col=t*16+m, row=quad*4+reg (+16w)
#pragma unroll
        for (int t = 0; t < 8; ++t) {
            int colv = t * 16 + m;
            float bv = bias[colv];
#pragma unroll
            for (int reg = 0; reg < 4; ++reg) {
                int rg = r0 + w * 16 + quad * 4 + reg;
                if (rg < N_NODES) {
                    float vv = fmaxf(acc[t][reg] + bv, 0.f);
                    hout[rg * C + colv] = f32_to_bf16(vv);
                }
            }
        }
    } else {
        // ---- phase 3: classifier fused — h2 tile to LDS, MFMA vs Wc ----
        __syncthreads();                      // all aggL/stg reads retired
#pragma unroll
        for (int t = 0; t < 8; ++t) {
            int colv = t * 16 + m;
            float bv = bias[colv];
#pragma unroll
            for (int reg = 0; reg < 4; ++reg) {
                int rl = w * 16 + quad * 4 + reg;
                float vv = fmaxf(acc[t][reg] + bv, 0.f);
                aggL[rl * ALD + colv] = f32_to_bf16(vv);
            }
        }
        // stage Wc planes into stg (7680 shorts = exactly AsX+Bs)
#pragma unroll
        for (int i = 0; i < 3; ++i) {
            int slot = tid + i * 256;         // 768 = 48 rows x 16 uint4
            int n = slot >> 4, kq = slot & 15;
            uint4 vv = *(const uint4*)&Wcb[n * C + kq * 8];
            *(uint4*)&stg[(kq >> 2) * (48 * 40) + n * 40 + (kq & 3) * 8] = vv;
        }
        __syncthreads();
        f32x4 acc2[3];
#pragma unroll
        for (int t = 0; t < 3; ++t) acc2[t] = (f32x4){0.f, 0.f, 0.f, 0.f};
#pragma unroll
        for (int kc = 0; kc < 4; ++kc) {
            bf16x8 af = *(const bf16x8*)&aggL[(w * 16 + m) * ALD + kc * 32 + quad * 8];
#pragma unroll
            for (int t = 0; t < 3; ++t) {
                bf16x8 bf = *(const bf16x8*)&stg[kc * (48 * 40) + (t * 16 + m) * 40 + quad * 8];
                acc2[t] = __builtin_amdgcn_mfma_f32_16x16x32_bf16(af, bf, acc2[t], 0, 0, 0);
            }
        }
#pragma unroll
        for (int t = 0; t < 3; ++t) {
            int col = t * 16 + m;
            if (col < NCLS) {
                float bvv = bc[col];
#pragma unroll
                for (int reg = 0; reg < 4; ++reg) {
                    int rg = r0 + w * 16 + quad * 4 + reg;
                    if (rg < N_NODES) out[rg * NCLS + col] = acc2[t][reg] + bvv;
                }
            }
        }
    }
}

extern "C" void kernel_launch(void* const* d_in, const int* in_sizes, int n_in,
                              void* d_out, int out_size, void* d_ws, size_t ws_size,
                              hipStream_t stream) {
    const float* x   = (const float*)d_in[0];
    const int*   ei  = (const int*)d_in[1];
    const float* Wl1 = (const float*)d_in[2];
    const float* Wr1 = (const float*)d_in[3];
    const float* b1  = (const float*)d_in[4];
    const float* Wl2 = (const float*)d_in[5];
    const float* Wr2 = (const float*)d_in[6];
    const float* b2  = (const float*)d_in[7];
    const float* Wc  = (const float*)d_in[8];
    const float* bc  = (const float*)d_in[9];
    const int* srcI = ei;              // edge_index[0]
    const int* dstI = ei + N_EDGES;    // edge_index[1]
    float* out = (float*)d_out;

    // workspace layout
    ushort_t* xb   = (ushort_t*)d_ws;                 // N*C bf16
    ushort_t* h1b  = xb + (size_t)N_NODES * C;        // N*C bf16
    ushort_t* Wbf1 = h1b + (size_t)N_NODES * C;       // 32768
    ushort_t* Wbf2 = Wbf1 + 32768;                    // 32768
    ushort_t* Wcb  = Wbf2 + 32768;                    // 6144
    ushort_t* csr16 = Wcb + 6144;                     // E (uint16)
    int* bucket_cnt = (int*)(csr16 + N_EDGES);        // 128
    int* row_ptr    = bucket_cnt + 128;               // N+1
    unsigned* bucket_data = (unsigned*)(row_ptr + N_NODES + 1);  // KB*BCAP

    // ---- conversions (1 launch) ----
    convert_all<<<280 + (N_NODES * C / 8 + 255) / 256, 256, 0, stream>>>(
        Wl1, Wr1, Wl2, Wr2, Wc, x, Wbf1, Wbf2, Wcb, xb);

    // ---- CSR build (bucketed two-pass, LDS write-combined) ----
    hipMemsetAsync(bucket_cnt, 0, 128 * sizeof(int), stream);
    bin_kernel<<<(N_EDGES + 4095) / 4096, 256, 0, stream>>>(srcI, dstI, bucket_cnt, bucket_data);
    build_kernel<<<KB, 256, 0, stream>>>(bucket_cnt, bucket_data, row_ptr, csr16);

    // ---- layer 1 (aggregate + GEMM fused) ----
    fused_layer<0><<<(N_NODES + 63) / 64, 256, 0, stream>>>(
        xb, row_ptr, csr16, Wbf1, b1, h1b, nullptr, nullptr, nullptr);

    // ---- layer 2 + classifier (fully fused) ----
    fused_layer<1><<<(N_NODES + 63) / 64, 256, 0, stream>>>(
        h1b, row_ptr, csr16, Wbf2, b2, nullptr, Wcb, bc, out);
}